// Round 1
// baseline (941.901 us; speedup 1.0000x reference)
//
#include <hip/hip_runtime.h>
#include <hip/hip_bf16.h>

#define NB 64
#define TT 512
#define VV 25
#define CINC 3
#define CH 64
#define FF 25
#define G4 100        // 4*FF
#define NSEQ 1600     // NB*VV

__device__ __forceinline__ float bf2f(__hip_bfloat16 b) { return __bfloat162float(b); }
__device__ __forceinline__ unsigned short f2bu(float f) {
    union { __hip_bfloat16 h; unsigned short u; } cv;
    cv.h = __float2bfloat16(f);
    return cv.u;
}
__device__ __forceinline__ float hsig(float x) {
    return fminf(fmaxf(fmaf(0.2f, x, 0.5f), 0.f), 1.f);
}
__device__ __forceinline__ float tanh_fast(float x) {
    float e = __expf(2.f * x);
    return fmaf(-2.f, __builtin_amdgcn_rcpf(e + 1.f), 1.f);
}
// load element i of an input whose fp32-ness was detected at runtime
__device__ __forceinline__ float ldin(const void* p, int i, int f32) {
    return f32 ? ((const float*)p)[i] : bf2f(((const __hip_bfloat16*)p)[i]);
}

// ws layout (bytes):
//   wbuf  @ 0       : 40,960  fp32 weights: Wc[0:192) bc[192:256) bl[256:356)
//                     Wl[384:6784) U[6784:9284) bias[9284:9909)
//   flags @ 40,960  : 256     int flags[7], 1 = input i is fp32
//   hst   @ 41,216  : 160,000 fp32 h state
//   cst   @ 201,216 : 160,000 fp32 c state
//   zxc   @ 361,216 : ct*320,000  bf16 z chunk [tl][seq][25 uint2], gate-interleaved
//   hsc   @ 361,216 + ct*320,000 : ct*160,000 fp32 h chunk [tl][seq][25]

// ---------------- Kd: per-input dtype detection ----------------
__global__ void k_detect(const unsigned short* a0, const unsigned short* a1,
                         const unsigned short* a2, const unsigned short* a3,
                         const unsigned short* a4, const unsigned short* a5,
                         const unsigned short* a6,
                         int s0, int s1, int s2, int s3, int s4, int s5, int s6,
                         int* flags) {
    const unsigned short* ps[7] = {a0, a1, a2, a3, a4, a5, a6};
    int ss[7] = {s0, s1, s2, s3, s4, s5, s6};
    int lane = threadIdx.x;
    for (int i = 0; i < 7; ++i) {
        int K = ss[i] / 2; if (K > 64) K = 64;
        int sane = 0;
        if (lane < K) {
            unsigned short u = ps[i][2 * lane];
            int e = (u >> 7) & 0xFF;
            sane = (e == 0) || (e >= 96 && e <= 159);
        }
        unsigned long long m = __ballot(sane);
        int cnt = __popcll(m);
        if (lane == 0) flags[i] = (2 * cnt < K) ? 1 : 0;
    }
}

// ---------------- K0: convert all weights -> fp32 wbuf; zero scan state ----------------
__global__ void k0_convert(const void* Wc, const void* bc, const void* Wl,
                           const void* Ul, const void* bl, const void* bias,
                           const int* __restrict__ flags,
                           float* __restrict__ wbuf,
                           float* __restrict__ hst, float* __restrict__ cst) {
    int f1 = flags[1], f2 = flags[2], f3 = flags[3];
    int f4 = flags[4], f5 = flags[5], f6 = flags[6];
    for (int i = threadIdx.x; i < 192;  i += 256) wbuf[i]        = ldin(Wc, i, f1);
    for (int i = threadIdx.x; i < 64;   i += 256) wbuf[192 + i]  = ldin(bc, i, f2);
    for (int i = threadIdx.x; i < 6400; i += 256) wbuf[384 + i]  = ldin(Wl, i, f3);
    for (int i = threadIdx.x; i < 2500; i += 256) wbuf[6784 + i] = ldin(Ul, i, f4);
    for (int i = threadIdx.x; i < 100;  i += 256) wbuf[256 + i]  = ldin(bl, i, f5);
    for (int i = threadIdx.x; i < 625;  i += 256) wbuf[9284 + i] = ldin(bias, i, f6);
    for (int i = threadIdx.x; i < NSEQ * FF; i += 256) { hst[i] = 0.f; cst[i] = 0.f; }
}

// ---------------- K1: zx chunk: row r = tl*NSEQ + n*25 + v ----------------
// zxc row layout (NEW): 25 uint2 words; word j = {bf16(zi_j), bf16(zf_j), bf16(zg_j), bf16(zo_j)}
// so k2 lane j fetches all 4 of its gate inputs with a single 8B load.
__global__ __launch_bounds__(256) void k1_zx(const void* __restrict__ x,
                                             const float* __restrict__ wbuf,
                                             const int* __restrict__ flags,
                                             __hip_bfloat16* __restrict__ zxc,
                                             int t0, int nrows) {
    int r = blockIdx.x * 256 + threadIdx.x;
    if (r >= nrows) return;
    int xf = flags[0];
    int tl = r / NSEQ;
    int rem = r - tl * NSEQ;
    int n = rem / VV;
    int v = rem - n * VV;
    int t = t0 + tl;
    int xb = ((n * TT + t) * VV + v) * CINC;
    float a0, a1, a2;
    if (xf) {
        const float* xp = (const float*)x;
        a0 = xp[xb]; a1 = xp[xb + 1]; a2 = xp[xb + 2];
    } else {
        const __hip_bfloat16* xp = (const __hip_bfloat16*)x;
        a0 = bf2f(xp[xb]); a1 = bf2f(xp[xb + 1]); a2 = bf2f(xp[xb + 2]);
    }

    const float* wc = wbuf;            // [k][64]
    const float* bc = wbuf + 192;
    const float* bl = wbuf + 256;
    const float* wl = wbuf + 384;      // [c][100]

    float acc[G4];
#pragma unroll
    for (int f = 0; f < G4; ++f) acc[f] = bl[f];

    for (int c = 0; c < CH; ++c) {
        float x1c = fmaxf(fmaf(a0, wc[c], fmaf(a1, wc[64 + c], fmaf(a2, wc[128 + c], bc[c]))), 0.f);
        const float* w = wl + c * G4;
#pragma unroll
        for (int f = 0; f < G4; ++f) acc[f] = fmaf(x1c, w[f], acc[f]);
    }

    uint2* zrow = (uint2*)(zxc + (size_t)r * G4);    // 200B rows, 8B-aligned
#pragma unroll
    for (int q = 0; q < 25; ++q) {
        uint2 p;
        p.x = (unsigned)f2bu(acc[q])      | ((unsigned)f2bu(acc[25 + q]) << 16);
        p.y = (unsigned)f2bu(acc[50 + q]) | ((unsigned)f2bu(acc[75 + q]) << 16);
        zrow[q] = p;
    }
}

// ---------------- K2: LSTM scan chunk, one wave per (n,v) sequence ----------------
// Grid-limited to 1600 waves (1.56 waves/SIMD): registers are free, latency is not.
// __launch_bounds__(64,1): allow ~160 VGPRs so all 100 U values stay resident
// (at the default budget the compiler re-loaded U from global every timestep).
// h-broadcast via v_readlane -> SGPR operand of v_fmac (no ds_bpermute in the
// recurrent critical path).  One uint2 load per lane per timestep for z.
__global__ __launch_bounds__(64, 1) void k2_scan(const __hip_bfloat16* __restrict__ zxc,
                                                 const float* __restrict__ wbuf,
                                                 float* __restrict__ hst,
                                                 float* __restrict__ cst,
                                                 float* __restrict__ hsc,
                                                 int ct) {
    int seq = blockIdx.x;                 // n*25 + v
    int j = threadIdx.x;
    int jj = (j < FF) ? j : 0;

    const float* uw = wbuf + 6784;        // U [k][100] fp32
    float Ui[FF], Uf[FF], Ug[FF], Uo[FF];
#pragma unroll
    for (int k = 0; k < FF; ++k) {
        const float* ur = uw + k * G4;
        Ui[k] = ur[jj];
        Uf[k] = ur[FF + jj];
        Ug[k] = ur[2 * FF + jj];
        Uo[k] = ur[3 * FF + jj];
    }

    float h = hst[seq * FF + jj];
    float c = cst[seq * FF + jj];

    const uint2* zw = (const uint2*)zxc;  // [tl][seq][25] uint2
    size_t zb0 = (size_t)seq * FF + jj;
    uint2 zcur = zw[zb0];

    for (int tl = 0; tl < ct; ++tl) {
        int tn = (tl + 1 < ct) ? tl + 1 : tl;
        uint2 znext = zw[(size_t)tn * (NSEQ * FF) + zb0];

        float gi = __uint_as_float(zcur.x << 16);
        float gf = __uint_as_float(zcur.x & 0xffff0000u);
        float gg = __uint_as_float(zcur.y << 16);
        float go = __uint_as_float(zcur.y & 0xffff0000u);

#pragma unroll
        for (int k = 0; k < FF; ++k) {
            float hk = __int_as_float(__builtin_amdgcn_readlane(__float_as_int(h), k));
            gi = fmaf(hk, Ui[k], gi);
            gf = fmaf(hk, Uf[k], gf);
            gg = fmaf(hk, Ug[k], gg);
            go = fmaf(hk, Uo[k], go);
        }
        c = fmaf(hsig(gf), c, hsig(gi) * tanh_fast(gg));
        h = hsig(go) * tanh_fast(c);

        if (j < FF) hsc[((size_t)tl * NSEQ + seq) * FF + j] = h;

        zcur = znext;
    }

    if (j < FF) {
        hst[seq * FF + j] = h;
        cst[seq * FF + j] = c;
    }
}

// ---------------- K3: attention + aggregation; grid = (ct, NB) ----------------
__global__ __launch_bounds__(64) void k3_attn(const void* __restrict__ x,
                                              const float* __restrict__ wbuf,
                                              const int* __restrict__ flags,
                                              const float* __restrict__ hsc,
                                              void* __restrict__ out,
                                              int t0) {
    int tl = blockIdx.x;
    int n  = blockIdx.y;
    int t = t0 + tl;
    int tid = threadIdx.x;
    int xf = flags[0];

    __shared__ float coefs[VV * 28];

    float wc0 = wbuf[tid], wc1 = wbuf[64 + tid], wc2 = wbuf[128 + tid];
    float bcv = wbuf[192 + tid];
    const float* biasf = wbuf + 9284;

    float x1col[VV];
    if (xf) {
        const float* xp = (const float*)x;
#pragma unroll
        for (int v = 0; v < VV; ++v) {
            int xb = ((n * TT + t) * VV + v) * CINC;
            float a0 = xp[xb], a1 = xp[xb + 1], a2 = xp[xb + 2];
            x1col[v] = fmaxf(fmaf(a0, wc0, fmaf(a1, wc1, fmaf(a2, wc2, bcv))), 0.f);
        }
    } else {
        const __hip_bfloat16* xp = (const __hip_bfloat16*)x;
#pragma unroll
        for (int v = 0; v < VV; ++v) {
            int xb = ((n * TT + t) * VV + v) * CINC;
            float a0 = bf2f(xp[xb]), a1 = bf2f(xp[xb + 1]), a2 = bf2f(xp[xb + 2]);
            x1col[v] = fmaxf(fmaf(a0, wc0, fmaf(a1, wc1, fmaf(a2, wc2, bcv))), 0.f);
        }
    }

    if (tid < VV) {
        size_t hb = ((size_t)tl * NSEQ + n * VV + tid) * FF;
        float lg[VV];
        float m = -1e30f;
#pragma unroll
        for (int w = 0; w < VV; ++w) {
            float hv = hsc[hb + w];
            float l = (hv > 0.f) ? hv : 0.2f * hv;
            l += biasf[tid * VV + w];
            lg[w] = l;
            m = fmaxf(m, l);
        }
        float s = 0.f;
#pragma unroll
        for (int w = 0; w < VV; ++w) { lg[w] = __expf(lg[w] - m); s += lg[w]; }
        float rs = 1.f / s;
#pragma unroll
        for (int w = 0; w < VV; ++w) coefs[tid * 28 + w] = lg[w] * rs;
    }
    __syncthreads();

    size_t ob = (size_t)(n * TT + t) * VV * CH + tid;
    if (xf) {
        float* outf = (float*)out;
#pragma unroll
        for (int v = 0; v < VV; ++v) {
            const float* cr = &coefs[v * 28];
            float acc = 0.f;
#pragma unroll
            for (int w = 0; w < VV; ++w) acc = fmaf(cr[w], x1col[w], acc);
            outf[ob + (size_t)v * CH] = acc;
        }
    } else {
        __hip_bfloat16* outb = (__hip_bfloat16*)out;
#pragma unroll
        for (int v = 0; v < VV; ++v) {
            const float* cr = &coefs[v * 28];
            float acc = 0.f;
#pragma unroll
            for (int w = 0; w < VV; ++w) acc = fmaf(cr[w], x1col[w], acc);
            outb[ob + (size_t)v * CH] = __float2bfloat16(acc);
        }
    }
}

extern "C" void kernel_launch(void* const* d_in, const int* in_sizes, int n_in,
                              void* d_out, int out_size, void* d_ws, size_t ws_size,
                              hipStream_t stream) {
    // d_in order: x, W_conv, b_conv, W_lstm, U_lstm, b_lstm, bias_mat
    char* wsb = (char*)d_ws;
    float* wbuf = (float*)wsb;
    int* flags = (int*)(wsb + 40960);
    float* hst = (float*)(wsb + 41216);
    float* cst = (float*)(wsb + 201216);

    // largest power-of-2 time chunk ct (divisor of 512) fitting the workspace
    const size_t fixed = 361216;
    int ct = 1;
    for (int c = 512; c >= 1; c >>= 1) {
        if (fixed + (size_t)c * 480000 <= ws_size) { ct = c; break; }
    }
    __hip_bfloat16* zxc = (__hip_bfloat16*)(wsb + fixed);
    float* hsc = (float*)(wsb + fixed + (size_t)ct * 320000);

    int nrows = ct * NSEQ;
    int k1blocks = (nrows + 255) / 256;

    k_detect<<<1, 64, 0, stream>>>(
        (const unsigned short*)d_in[0], (const unsigned short*)d_in[1],
        (const unsigned short*)d_in[2], (const unsigned short*)d_in[3],
        (const unsigned short*)d_in[4], (const unsigned short*)d_in[5],
        (const unsigned short*)d_in[6],
        in_sizes[0], in_sizes[1], in_sizes[2], in_sizes[3],
        in_sizes[4], in_sizes[5], in_sizes[6], flags);
    k0_convert<<<1, 256, 0, stream>>>(d_in[1], d_in[2], d_in[3], d_in[4],
                                      d_in[5], d_in[6], flags, wbuf, hst, cst);
    for (int t0 = 0; t0 < TT; t0 += ct) {
        k1_zx<<<k1blocks, 256, 0, stream>>>(d_in[0], wbuf, flags, zxc, t0, nrows);
        k2_scan<<<NSEQ, 64, 0, stream>>>(zxc, wbuf, hst, cst, hsc, ct);
        k3_attn<<<dim3(ct, NB), 64, 0, stream>>>(d_in[0], wbuf, flags, hsc, d_out, t0);
    }
}

// Round 2
// 740.027 us; speedup vs baseline: 1.2728x; 1.2728x over previous
//
#include <hip/hip_runtime.h>
#include <hip/hip_bf16.h>

#define NB 64
#define TT 512
#define VV 25
#define CINC 3
#define CH 64
#define FF 25
#define G4 100        // 4*FF
#define NSEQ 1600     // NB*VV

__device__ __forceinline__ float bf2f(__hip_bfloat16 b) { return __bfloat162float(b); }
__device__ __forceinline__ unsigned short f2bu(float f) {
    union { __hip_bfloat16 h; unsigned short u; } cv;
    cv.h = __float2bfloat16(f);
    return cv.u;
}
__device__ __forceinline__ float hsig(float x) {
    return fminf(fmaxf(fmaf(0.2f, x, 0.5f), 0.f), 1.f);
}
__device__ __forceinline__ float tanh_fast(float x) {
    float e = __expf(2.f * x);
    return fmaf(-2.f, __builtin_amdgcn_rcpf(e + 1.f), 1.f);
}
// load element i of an input whose fp32-ness was detected at runtime
__device__ __forceinline__ float ldin(const void* p, int i, int f32) {
    return f32 ? ((const float*)p)[i] : bf2f(((const __hip_bfloat16*)p)[i]);
}

// ws layout (bytes):
//   wbuf  @ 0       : 40,960  fp32 weights: Wc[0:192) bc[192:256) bl[256:356)
//                     Wl[384:6784) U[6784:9284) bias[9284:9909)
//   flags @ 40,960  : 256     int flags[7], 1 = input i is fp32
//   hst   @ 41,216  : 160,000 fp32 h state
//   cst   @ 201,216 : 160,000 fp32 c state
//   zxc   @ 361,216 : ct*320,000  z chunk [tl][seq][50 u32]; word w = (bf16 acc[w], bf16 acc[w+50])
//   hsc   @ 361,216 + ct*320,000 : ct*160,000 fp32 h chunk [tl][seq][25]

// ---------------- Kd: per-input dtype detection ----------------
__global__ void k_detect(const unsigned short* a0, const unsigned short* a1,
                         const unsigned short* a2, const unsigned short* a3,
                         const unsigned short* a4, const unsigned short* a5,
                         const unsigned short* a6,
                         int s0, int s1, int s2, int s3, int s4, int s5, int s6,
                         int* flags) {
    const unsigned short* ps[7] = {a0, a1, a2, a3, a4, a5, a6};
    int ss[7] = {s0, s1, s2, s3, s4, s5, s6};
    int lane = threadIdx.x;
    for (int i = 0; i < 7; ++i) {
        int K = ss[i] / 2; if (K > 64) K = 64;
        int sane = 0;
        if (lane < K) {
            unsigned short u = ps[i][2 * lane];
            int e = (u >> 7) & 0xFF;
            sane = (e == 0) || (e >= 96 && e <= 159);
        }
        unsigned long long m = __ballot(sane);
        int cnt = __popcll(m);
        if (lane == 0) flags[i] = (2 * cnt < K) ? 1 : 0;
    }
}

// ---------------- K0: convert all weights -> fp32 wbuf; zero scan state ----------------
__global__ void k0_convert(const void* Wc, const void* bc, const void* Wl,
                           const void* Ul, const void* bl, const void* bias,
                           const int* __restrict__ flags,
                           float* __restrict__ wbuf,
                           float* __restrict__ hst, float* __restrict__ cst) {
    int f1 = flags[1], f2 = flags[2], f3 = flags[3];
    int f4 = flags[4], f5 = flags[5], f6 = flags[6];
    for (int i = threadIdx.x; i < 192;  i += 256) wbuf[i]        = ldin(Wc, i, f1);
    for (int i = threadIdx.x; i < 64;   i += 256) wbuf[192 + i]  = ldin(bc, i, f2);
    for (int i = threadIdx.x; i < 6400; i += 256) wbuf[384 + i]  = ldin(Wl, i, f3);
    for (int i = threadIdx.x; i < 2500; i += 256) wbuf[6784 + i] = ldin(Ul, i, f4);
    for (int i = threadIdx.x; i < 100;  i += 256) wbuf[256 + i]  = ldin(bl, i, f5);
    for (int i = threadIdx.x; i < 625;  i += 256) wbuf[9284 + i] = ldin(bias, i, f6);
    for (int i = threadIdx.x; i < NSEQ * FF; i += 256) { hst[i] = 0.f; cst[i] = 0.f; }
}

// ---------------- K1: zx chunk: row r = tl*NSEQ + n*25 + v ----------------
// zxc row layout: 50 u32 words; word w = bf16(acc[w]) | bf16(acc[w+50])<<16, w in [0,50).
// k2 lane (hi,j) reads word hi*25+j: lower half gets (zi_j, zg_j), upper gets (zf_j, zo_j).
__global__ __launch_bounds__(256) void k1_zx(const void* __restrict__ x,
                                             const float* __restrict__ wbuf,
                                             const int* __restrict__ flags,
                                             unsigned* __restrict__ zxc,
                                             int t0, int nrows) {
    int r = blockIdx.x * 256 + threadIdx.x;
    if (r >= nrows) return;
    int xf = flags[0];
    int tl = r / NSEQ;
    int rem = r - tl * NSEQ;
    int n = rem / VV;
    int v = rem - n * VV;
    int t = t0 + tl;
    int xb = ((n * TT + t) * VV + v) * CINC;
    float a0, a1, a2;
    if (xf) {
        const float* xp = (const float*)x;
        a0 = xp[xb]; a1 = xp[xb + 1]; a2 = xp[xb + 2];
    } else {
        const __hip_bfloat16* xp = (const __hip_bfloat16*)x;
        a0 = bf2f(xp[xb]); a1 = bf2f(xp[xb + 1]); a2 = bf2f(xp[xb + 2]);
    }

    const float* wc = wbuf;            // [k][64]
    const float* bc = wbuf + 192;
    const float* bl = wbuf + 256;
    const float* wl = wbuf + 384;      // [c][100]

    float acc[G4];
#pragma unroll
    for (int f = 0; f < G4; ++f) acc[f] = bl[f];

    for (int c = 0; c < CH; ++c) {
        float x1c = fmaxf(fmaf(a0, wc[c], fmaf(a1, wc[64 + c], fmaf(a2, wc[128 + c], bc[c]))), 0.f);
        const float* w = wl + c * G4;
#pragma unroll
        for (int f = 0; f < G4; ++f) acc[f] = fmaf(x1c, w[f], acc[f]);
    }

    uint2* zrow = (uint2*)(zxc + (size_t)r * 50);    // 200B rows, 8B-aligned
#pragma unroll
    for (int q = 0; q < 25; ++q) {
        uint2 p;
        p.x = (unsigned)f2bu(acc[2 * q])     | ((unsigned)f2bu(acc[2 * q + 50]) << 16);
        p.y = (unsigned)f2bu(acc[2 * q + 1]) | ((unsigned)f2bu(acc[2 * q + 51]) << 16);
        zrow[q] = p;
    }
}

// ---------------- K2: LSTM scan chunk, one wave per (n,v) sequence ----------------
// Lane split: lanes 0-24 own gates (i_j, g_j); lanes 32-56 own (f_j, o_j).
// Per lane: 50 recurrent FMAs + 50 resident U values (fits the default VGPR
// budget, so LICM can finally hoist U out of the loop — round-1 showed the
// allocator refuses at 100+ values and re-loads U every timestep instead).
// Both halves compute c,h redundantly-correctly so readlane(h, k<25) is valid.
__global__ __launch_bounds__(64, 1) void k2_scan(const unsigned* __restrict__ zxc,
                                                 const float* __restrict__ wbuf,
                                                 float* __restrict__ hst,
                                                 float* __restrict__ cst,
                                                 float* __restrict__ hsc,
                                                 int ct) {
    int seq = blockIdx.x;                 // n*25 + v
    int L = threadIdx.x;
    int hi = L >> 5;                      // 0: (i,g) half, 1: (f,o) half
    int lo = L & 31;
    int j = (lo < FF) ? lo : 0;           // lanes 25-31/57-63 duplicate j=0

    int colA = hi * FF + j;               // i_j or f_j
    int colB = 2 * FF + hi * FF + j;      // g_j or o_j
    const float* uw = wbuf + 6784;        // U [k][100] fp32
    float UA[FF], UB[FF];
#pragma unroll
    for (int k = 0; k < FF; ++k) {
        UA[k] = uw[k * G4 + colA];
        UB[k] = uw[k * G4 + colB];
    }

    float h = hst[seq * FF + j];
    float c = cst[seq * FF + j];

    const unsigned* zpt = zxc + (size_t)seq * 50 + (hi * FF + j);
    const size_t zstride = (size_t)NSEQ * 50;
    unsigned zc = zpt[0];

    for (int tl = 0; tl < ct; ++tl) {
        int tn = (tl + 1 < ct) ? tl + 1 : tl;
        unsigned zn = zpt[(size_t)tn * zstride];

        float gA = __uint_as_float(zc << 16);          // i_j / f_j input proj
        float gB = __uint_as_float(zc & 0xffff0000u);  // g_j / o_j input proj

#pragma unroll
        for (int k = 0; k < FF; ++k) {
            float hk = __int_as_float(__builtin_amdgcn_readlane(__float_as_int(h), k));
            gA = fmaf(hk, UA[k], gA);
            gB = fmaf(hk, UB[k], gB);
        }

        float sA = hsig(gA);                   // î (lower) / f̂ (upper)
        float sB = hsig(gB);                   // upper: ô
        float tB = tanh_fast(gB);              // lower: g̃
        float aB = hi ? sB : tB;

        float pA = __shfl_xor(sA, 32);         // lower← f̂ , upper← î
        float pB = __shfl_xor(aB, 32);         // lower← ô , upper← g̃

        float fgate = hi ? sA : pA;
        float igate = hi ? pA : sA;
        float ggate = hi ? pB : aB;
        float ogate = hi ? aB : pB;

        c = fmaf(fgate, c, igate * ggate);
        h = ogate * tanh_fast(c);

        if (L < FF) hsc[((size_t)tl * NSEQ + seq) * FF + L] = h;

        zc = zn;
    }

    if (L < FF) {
        hst[seq * FF + L] = h;
        cst[seq * FF + L] = c;
    }
}

// ---------------- K3: attention + aggregation; grid = (ct, NB) ----------------
__global__ __launch_bounds__(64) void k3_attn(const void* __restrict__ x,
                                              const float* __restrict__ wbuf,
                                              const int* __restrict__ flags,
                                              const float* __restrict__ hsc,
                                              void* __restrict__ out,
                                              int t0) {
    int tl = blockIdx.x;
    int n  = blockIdx.y;
    int t = t0 + tl;
    int tid = threadIdx.x;
    int xf = flags[0];

    __shared__ float coefs[VV * 28];

    float wc0 = wbuf[tid], wc1 = wbuf[64 + tid], wc2 = wbuf[128 + tid];
    float bcv = wbuf[192 + tid];
    const float* biasf = wbuf + 9284;

    float x1col[VV];
    if (xf) {
        const float* xp = (const float*)x;
#pragma unroll
        for (int v = 0; v < VV; ++v) {
            int xb = ((n * TT + t) * VV + v) * CINC;
            float a0 = xp[xb], a1 = xp[xb + 1], a2 = xp[xb + 2];
            x1col[v] = fmaxf(fmaf(a0, wc0, fmaf(a1, wc1, fmaf(a2, wc2, bcv))), 0.f);
        }
    } else {
        const __hip_bfloat16* xp = (const __hip_bfloat16*)x;
#pragma unroll
        for (int v = 0; v < VV; ++v) {
            int xb = ((n * TT + t) * VV + v) * CINC;
            float a0 = bf2f(xp[xb]), a1 = bf2f(xp[xb + 1]), a2 = bf2f(xp[xb + 2]);
            x1col[v] = fmaxf(fmaf(a0, wc0, fmaf(a1, wc1, fmaf(a2, wc2, bcv))), 0.f);
        }
    }

    if (tid < VV) {
        size_t hb = ((size_t)tl * NSEQ + n * VV + tid) * FF;
        float lg[VV];
        float m = -1e30f;
#pragma unroll
        for (int w = 0; w < VV; ++w) {
            float hv = hsc[hb + w];
            float l = (hv > 0.f) ? hv : 0.2f * hv;
            l += biasf[tid * VV + w];
            lg[w] = l;
            m = fmaxf(m, l);
        }
        float s = 0.f;
#pragma unroll
        for (int w = 0; w < VV; ++w) { lg[w] = __expf(lg[w] - m); s += lg[w]; }
        float rs = 1.f / s;
#pragma unroll
        for (int w = 0; w < VV; ++w) coefs[tid * 28 + w] = lg[w] * rs;
    }
    __syncthreads();

    size_t ob = (size_t)(n * TT + t) * VV * CH + tid;
    if (xf) {
        float* outf = (float*)out;
#pragma unroll
        for (int v = 0; v < VV; ++v) {
            const float* cr = &coefs[v * 28];
            float acc = 0.f;
#pragma unroll
            for (int w = 0; w < VV; ++w) acc = fmaf(cr[w], x1col[w], acc);
            outf[ob + (size_t)v * CH] = acc;
        }
    } else {
        __hip_bfloat16* outb = (__hip_bfloat16*)out;
#pragma unroll
        for (int v = 0; v < VV; ++v) {
            const float* cr = &coefs[v * 28];
            float acc = 0.f;
#pragma unroll
            for (int w = 0; w < VV; ++w) acc = fmaf(cr[w], x1col[w], acc);
            outb[ob + (size_t)v * CH] = __float2bfloat16(acc);
        }
    }
}

extern "C" void kernel_launch(void* const* d_in, const int* in_sizes, int n_in,
                              void* d_out, int out_size, void* d_ws, size_t ws_size,
                              hipStream_t stream) {
    // d_in order: x, W_conv, b_conv, W_lstm, U_lstm, b_lstm, bias_mat
    char* wsb = (char*)d_ws;
    float* wbuf = (float*)wsb;
    int* flags = (int*)(wsb + 40960);
    float* hst = (float*)(wsb + 41216);
    float* cst = (float*)(wsb + 201216);

    // largest power-of-2 time chunk ct (divisor of 512) fitting the workspace
    const size_t fixed = 361216;
    int ct = 1;
    for (int c = 512; c >= 1; c >>= 1) {
        if (fixed + (size_t)c * 480000 <= ws_size) { ct = c; break; }
    }
    unsigned* zxc = (unsigned*)(wsb + fixed);
    float* hsc = (float*)(wsb + fixed + (size_t)ct * 320000);

    int nrows = ct * NSEQ;
    int k1blocks = (nrows + 255) / 256;

    k_detect<<<1, 64, 0, stream>>>(
        (const unsigned short*)d_in[0], (const unsigned short*)d_in[1],
        (const unsigned short*)d_in[2], (const unsigned short*)d_in[3],
        (const unsigned short*)d_in[4], (const unsigned short*)d_in[5],
        (const unsigned short*)d_in[6],
        in_sizes[0], in_sizes[1], in_sizes[2], in_sizes[3],
        in_sizes[4], in_sizes[5], in_sizes[6], flags);
    k0_convert<<<1, 256, 0, stream>>>(d_in[1], d_in[2], d_in[3], d_in[4],
                                      d_in[5], d_in[6], flags, wbuf, hst, cst);
    for (int t0 = 0; t0 < TT; t0 += ct) {
        k1_zx<<<k1blocks, 256, 0, stream>>>(d_in[0], wbuf, flags, zxc, t0, nrows);
        k2_scan<<<NSEQ, 64, 0, stream>>>(zxc, wbuf, hst, cst, hsc, ct);
        k3_attn<<<dim3(ct, NB), 64, 0, stream>>>(d_in[0], wbuf, flags, hsc, d_out, t0);
    }
}

// Round 3
// 731.580 us; speedup vs baseline: 1.2875x; 1.0115x over previous
//
#include <hip/hip_runtime.h>
#include <hip/hip_bf16.h>

#define NB 64
#define TT 512
#define VV 25
#define CINC 3
#define CH 64
#define FF 25
#define G4 100        // 4*FF
#define NSEQ 1600     // NB*VV

__device__ __forceinline__ float bf2f(__hip_bfloat16 b) { return __bfloat162float(b); }
__device__ __forceinline__ unsigned short f2bu(float f) {
    union { __hip_bfloat16 h; unsigned short u; } cv;
    cv.h = __float2bfloat16(f);
    return cv.u;
}
__device__ __forceinline__ float hsig(float x) {
    return fminf(fmaxf(fmaf(0.2f, x, 0.5f), 0.f), 1.f);
}
__device__ __forceinline__ float tanh_fast(float x) {
    float e = __expf(2.f * x);
    return fmaf(-2.f, __builtin_amdgcn_rcpf(e + 1.f), 1.f);
}
// load element i of an input whose fp32-ness was detected at runtime
__device__ __forceinline__ float ldin(const void* p, int i, int f32) {
    return f32 ? ((const float*)p)[i] : bf2f(((const __hip_bfloat16*)p)[i]);
}
__device__ __forceinline__ float rdlane(float v, int lane) {
    return __int_as_float(__builtin_amdgcn_readlane(__float_as_int(v), lane));
}

// ws layout (bytes):
//   wbuf  @ 0       : 40,960  fp32 weights: Wc[0:192) bc[192:256) bl[256:356)
//                     Wl[384:6784) U[6784:9284) bias[9284:9909)
//   flags @ 40,960  : 256     int flags[7], 1 = input i is fp32
//   hst   @ 41,216  : 160,000 fp32 h state
//   cst   @ 201,216 : 160,000 fp32 c state
//   zxc   @ 361,216 : ct*320,000  z chunk [tl][seq][50 u32]; word w = (bf16 acc[w], bf16 acc[w+50])
//   hsc   @ 361,216 + ct*320,000 : ct*160,000 fp32 h chunk [tl][seq][25]

// ---------------- Kd: per-input dtype detection ----------------
__global__ void k_detect(const unsigned short* a0, const unsigned short* a1,
                         const unsigned short* a2, const unsigned short* a3,
                         const unsigned short* a4, const unsigned short* a5,
                         const unsigned short* a6,
                         int s0, int s1, int s2, int s3, int s4, int s5, int s6,
                         int* flags) {
    const unsigned short* ps[7] = {a0, a1, a2, a3, a4, a5, a6};
    int ss[7] = {s0, s1, s2, s3, s4, s5, s6};
    int lane = threadIdx.x;
    for (int i = 0; i < 7; ++i) {
        int K = ss[i] / 2; if (K > 64) K = 64;
        int sane = 0;
        if (lane < K) {
            unsigned short u = ps[i][2 * lane];
            int e = (u >> 7) & 0xFF;
            sane = (e == 0) || (e >= 96 && e <= 159);
        }
        unsigned long long m = __ballot(sane);
        int cnt = __popcll(m);
        if (lane == 0) flags[i] = (2 * cnt < K) ? 1 : 0;
    }
}

// ---------------- K0: convert all weights -> fp32 wbuf; zero scan state ----------------
__global__ void k0_convert(const void* Wc, const void* bc, const void* Wl,
                           const void* Ul, const void* bl, const void* bias,
                           const int* __restrict__ flags,
                           float* __restrict__ wbuf,
                           float* __restrict__ hst, float* __restrict__ cst) {
    int f1 = flags[1], f2 = flags[2], f3 = flags[3];
    int f4 = flags[4], f5 = flags[5], f6 = flags[6];
    for (int i = threadIdx.x; i < 192;  i += 256) wbuf[i]        = ldin(Wc, i, f1);
    for (int i = threadIdx.x; i < 64;   i += 256) wbuf[192 + i]  = ldin(bc, i, f2);
    for (int i = threadIdx.x; i < 6400; i += 256) wbuf[384 + i]  = ldin(Wl, i, f3);
    for (int i = threadIdx.x; i < 2500; i += 256) wbuf[6784 + i] = ldin(Ul, i, f4);
    for (int i = threadIdx.x; i < 100;  i += 256) wbuf[256 + i]  = ldin(bl, i, f5);
    for (int i = threadIdx.x; i < 625;  i += 256) wbuf[9284 + i] = ldin(bias, i, f6);
    for (int i = threadIdx.x; i < NSEQ * FF; i += 256) { hst[i] = 0.f; cst[i] = 0.f; }
}

// ---------------- K1: zx chunk: row r = tl*NSEQ + n*25 + v ----------------
// zxc row layout: 50 u32 words; word w = bf16(acc[w]) | bf16(acc[w+50])<<16, w in [0,50).
// k2 lane (hi,j) reads word hi*25+j: lower half gets (zi_j, zg_j), upper gets (zf_j, zo_j).
__global__ __launch_bounds__(256) void k1_zx(const void* __restrict__ x,
                                             const float* __restrict__ wbuf,
                                             const int* __restrict__ flags,
                                             unsigned* __restrict__ zxc,
                                             int t0, int nrows) {
    int r = blockIdx.x * 256 + threadIdx.x;
    if (r >= nrows) return;
    int xf = flags[0];
    int tl = r / NSEQ;
    int rem = r - tl * NSEQ;
    int n = rem / VV;
    int v = rem - n * VV;
    int t = t0 + tl;
    int xb = ((n * TT + t) * VV + v) * CINC;
    float a0, a1, a2;
    if (xf) {
        const float* xp = (const float*)x;
        a0 = xp[xb]; a1 = xp[xb + 1]; a2 = xp[xb + 2];
    } else {
        const __hip_bfloat16* xp = (const __hip_bfloat16*)x;
        a0 = bf2f(xp[xb]); a1 = bf2f(xp[xb + 1]); a2 = bf2f(xp[xb + 2]);
    }

    const float* wc = wbuf;            // [k][64]
    const float* bc = wbuf + 192;
    const float* bl = wbuf + 256;
    const float* wl = wbuf + 384;      // [c][100]

    float acc[G4];
#pragma unroll
    for (int f = 0; f < G4; ++f) acc[f] = bl[f];

    for (int c = 0; c < CH; ++c) {
        float x1c = fmaxf(fmaf(a0, wc[c], fmaf(a1, wc[64 + c], fmaf(a2, wc[128 + c], bc[c]))), 0.f);
        const float* w = wl + c * G4;
#pragma unroll
        for (int f = 0; f < G4; ++f) acc[f] = fmaf(x1c, w[f], acc[f]);
    }

    uint2* zrow = (uint2*)(zxc + (size_t)r * 50);    // 200B rows, 8B-aligned
#pragma unroll
    for (int q = 0; q < 25; ++q) {
        uint2 p;
        p.x = (unsigned)f2bu(acc[2 * q])     | ((unsigned)f2bu(acc[2 * q + 50]) << 16);
        p.y = (unsigned)f2bu(acc[2 * q + 1]) | ((unsigned)f2bu(acc[2 * q + 51]) << 16);
        zrow[q] = p;
    }
}

// ---------------- K2: LSTM scan chunk, one wave per (n,v) sequence ----------------
// Lane split: lanes 0-24 own gates (i_j, g_j); lanes 32-56 own (f_j, o_j).
// Round-2 evidence: even at 50 U values / __launch_bounds__(64,1), the
// allocator re-loads U from global every timestep (VGPR_Count=36).  Fix:
// asm optimization barrier pins each U value in a VGPR — the value becomes
// opaque, so it CANNOT be re-materialized from memory.  Registers are free
// here (grid-limited occupancy, 1.56 waves/SIMD).
// Gate accumulation split into 4 partials to cut the dependent-FMA chain.
__global__ __launch_bounds__(64, 1) void k2_scan(const unsigned* __restrict__ zxc,
                                                 const float* __restrict__ wbuf,
                                                 float* __restrict__ hst,
                                                 float* __restrict__ cst,
                                                 float* __restrict__ hsc,
                                                 int ct) {
    int seq = blockIdx.x;                 // n*25 + v
    int L = threadIdx.x;
    int hi = L >> 5;                      // 0: (i,g) half, 1: (f,o) half
    int lo = L & 31;
    int j = (lo < FF) ? lo : 0;           // lanes 25-31/57-63 duplicate j=0

    int colA = hi * FF + j;               // i_j or f_j
    int colB = 2 * FF + hi * FF + j;      // g_j or o_j
    const float* uw = wbuf + 6784;        // U [k][100] fp32
    float UA[FF], UB[FF];
#pragma unroll
    for (int k = 0; k < FF; ++k) {
        UA[k] = uw[k * G4 + colA];
        UB[k] = uw[k * G4 + colB];
        // pin in VGPR: value is opaque after this, cannot be re-loaded in-loop
        asm volatile("" : "+v"(UA[k]));
        asm volatile("" : "+v"(UB[k]));
    }

    float h = hst[seq * FF + j];
    float c = cst[seq * FF + j];

    const unsigned* zpt = zxc + (size_t)seq * 50 + (hi * FF + j);
    const size_t zstride = (size_t)NSEQ * 50;   // u32 elements per time slice
    unsigned zc = zpt[0];
    const unsigned* zp = zpt + zstride;         // next-timestep pointer, bumped per iter

    for (int tl = 0; tl < ct; ++tl) {
        const unsigned* pz = (tl + 1 < ct) ? zp : (zp - zstride);  // clamp: stay in bounds
        unsigned zn = *pz;
        zp += zstride;

        // 4 independent partial accumulators per gate: dep chain 25 -> ~7 FMAs
        float a0 = __uint_as_float(zc << 16);          // i_j / f_j input proj
        float b0 = __uint_as_float(zc & 0xffff0000u);  // g_j / o_j input proj
        float a1 = 0.f, a2 = 0.f, a3 = 0.f;
        float b1 = 0.f, b2 = 0.f, b3 = 0.f;

#pragma unroll
        for (int k = 0; k < 24; k += 4) {
            float h0 = rdlane(h, k),     h1 = rdlane(h, k + 1);
            float h2 = rdlane(h, k + 2), h3 = rdlane(h, k + 3);
            a0 = fmaf(h0, UA[k], a0);     b0 = fmaf(h0, UB[k], b0);
            a1 = fmaf(h1, UA[k + 1], a1); b1 = fmaf(h1, UB[k + 1], b1);
            a2 = fmaf(h2, UA[k + 2], a2); b2 = fmaf(h2, UB[k + 2], b2);
            a3 = fmaf(h3, UA[k + 3], a3); b3 = fmaf(h3, UB[k + 3], b3);
        }
        {
            float h24 = rdlane(h, 24);
            a0 = fmaf(h24, UA[24], a0);
            b0 = fmaf(h24, UB[24], b0);
        }
        float gA = (a0 + a1) + (a2 + a3);
        float gB = (b0 + b1) + (b2 + b3);

        float sA = hsig(gA);                   // î (lower) / f̂ (upper)
        float sB = hsig(gB);                   // upper: ô
        float tB = tanh_fast(gB);              // lower: g̃
        float aB = hi ? sB : tB;

        float pA = __shfl_xor(sA, 32);         // lower← f̂ , upper← î
        float pB = __shfl_xor(aB, 32);         // lower← ô , upper← g̃

        float fgate = hi ? sA : pA;
        float igate = hi ? pA : sA;
        float ggate = hi ? pB : aB;
        float ogate = hi ? aB : pB;

        c = fmaf(fgate, c, igate * ggate);
        h = ogate * tanh_fast(c);

        if (L < FF) hsc[((size_t)tl * NSEQ + seq) * FF + L] = h;

        zc = zn;
    }

    if (L < FF) {
        hst[seq * FF + L] = h;
        cst[seq * FF + L] = c;
    }
}

// ---------------- K3: attention + aggregation; grid = (ct, NB) ----------------
__global__ __launch_bounds__(64) void k3_attn(const void* __restrict__ x,
                                              const float* __restrict__ wbuf,
                                              const int* __restrict__ flags,
                                              const float* __restrict__ hsc,
                                              void* __restrict__ out,
                                              int t0) {
    int tl = blockIdx.x;
    int n  = blockIdx.y;
    int t = t0 + tl;
    int tid = threadIdx.x;
    int xf = flags[0];

    __shared__ float coefs[VV * 28];

    float wc0 = wbuf[tid], wc1 = wbuf[64 + tid], wc2 = wbuf[128 + tid];
    float bcv = wbuf[192 + tid];
    const float* biasf = wbuf + 9284;

    float x1col[VV];
    if (xf) {
        const float* xp = (const float*)x;
#pragma unroll
        for (int v = 0; v < VV; ++v) {
            int xb = ((n * TT + t) * VV + v) * CINC;
            float a0 = xp[xb], a1 = xp[xb + 1], a2 = xp[xb + 2];
            x1col[v] = fmaxf(fmaf(a0, wc0, fmaf(a1, wc1, fmaf(a2, wc2, bcv))), 0.f);
        }
    } else {
        const __hip_bfloat16* xp = (const __hip_bfloat16*)x;
#pragma unroll
        for (int v = 0; v < VV; ++v) {
            int xb = ((n * TT + t) * VV + v) * CINC;
            float a0 = bf2f(xp[xb]), a1 = bf2f(xp[xb + 1]), a2 = bf2f(xp[xb + 2]);
            x1col[v] = fmaxf(fmaf(a0, wc0, fmaf(a1, wc1, fmaf(a2, wc2, bcv))), 0.f);
        }
    }

    if (tid < VV) {
        size_t hb = ((size_t)tl * NSEQ + n * VV + tid) * FF;
        float lg[VV];
        float m = -1e30f;
#pragma unroll
        for (int w = 0; w < VV; ++w) {
            float hv = hsc[hb + w];
            float l = (hv > 0.f) ? hv : 0.2f * hv;
            l += biasf[tid * VV + w];
            lg[w] = l;
            m = fmaxf(m, l);
        }
        float s = 0.f;
#pragma unroll
        for (int w = 0; w < VV; ++w) { lg[w] = __expf(lg[w] - m); s += lg[w]; }
        float rs = 1.f / s;
#pragma unroll
        for (int w = 0; w < VV; ++w) coefs[tid * 28 + w] = lg[w] * rs;
    }
    __syncthreads();

    size_t ob = (size_t)(n * TT + t) * VV * CH + tid;
    if (xf) {
        float* outf = (float*)out;
#pragma unroll
        for (int v = 0; v < VV; ++v) {
            const float* cr = &coefs[v * 28];
            float acc = 0.f;
#pragma unroll
            for (int w = 0; w < VV; ++w) acc = fmaf(cr[w], x1col[w], acc);
            outf[ob + (size_t)v * CH] = acc;
        }
    } else {
        __hip_bfloat16* outb = (__hip_bfloat16*)out;
#pragma unroll
        for (int v = 0; v < VV; ++v) {
            const float* cr = &coefs[v * 28];
            float acc = 0.f;
#pragma unroll
            for (int w = 0; w < VV; ++w) acc = fmaf(cr[w], x1col[w], acc);
            outb[ob + (size_t)v * CH] = __float2bfloat16(acc);
        }
    }
}

extern "C" void kernel_launch(void* const* d_in, const int* in_sizes, int n_in,
                              void* d_out, int out_size, void* d_ws, size_t ws_size,
                              hipStream_t stream) {
    // d_in order: x, W_conv, b_conv, W_lstm, U_lstm, b_lstm, bias_mat
    char* wsb = (char*)d_ws;
    float* wbuf = (float*)wsb;
    int* flags = (int*)(wsb + 40960);
    float* hst = (float*)(wsb + 41216);
    float* cst = (float*)(wsb + 201216);

    // largest power-of-2 time chunk ct (divisor of 512) fitting the workspace
    const size_t fixed = 361216;
    int ct = 1;
    for (int c = 512; c >= 1; c >>= 1) {
        if (fixed + (size_t)c * 480000 <= ws_size) { ct = c; break; }
    }
    unsigned* zxc = (unsigned*)(wsb + fixed);
    float* hsc = (float*)(wsb + fixed + (size_t)ct * 320000);

    int nrows = ct * NSEQ;
    int k1blocks = (nrows + 255) / 256;

    k_detect<<<1, 64, 0, stream>>>(
        (const unsigned short*)d_in[0], (const unsigned short*)d_in[1],
        (const unsigned short*)d_in[2], (const unsigned short*)d_in[3],
        (const unsigned short*)d_in[4], (const unsigned short*)d_in[5],
        (const unsigned short*)d_in[6],
        in_sizes[0], in_sizes[1], in_sizes[2], in_sizes[3],
        in_sizes[4], in_sizes[5], in_sizes[6], flags);
    k0_convert<<<1, 256, 0, stream>>>(d_in[1], d_in[2], d_in[3], d_in[4],
                                      d_in[5], d_in[6], flags, wbuf, hst, cst);
    for (int t0 = 0; t0 < TT; t0 += ct) {
        k1_zx<<<k1blocks, 256, 0, stream>>>(d_in[0], wbuf, flags, zxc, t0, nrows);
        k2_scan<<<NSEQ, 64, 0, stream>>>(zxc, wbuf, hst, cst, hsc, ct);
        k3_attn<<<dim3(ct, NB), 64, 0, stream>>>(d_in[0], wbuf, flags, hsc, d_out, t0);
    }
}